// Round 1
// baseline (656.361 us; speedup 1.0000x reference)
//
#include <hip/hip_runtime.h>

#define D_MODEL 256
#define NSEQ    8192
#define PV_GROUPS 8

typedef _Float16 half8 __attribute__((ext_vector_type(8)));
typedef _Float16 half4 __attribute__((ext_vector_type(4)));
typedef float    f32x4 __attribute__((ext_vector_type(4)));

__device__ __forceinline__ half8 cvt8(f32x4 a, f32x4 b) {
  half8 h;
  h[0]=(_Float16)a[0]; h[1]=(_Float16)a[1]; h[2]=(_Float16)a[2]; h[3]=(_Float16)a[3];
  h[4]=(_Float16)b[0]; h[5]=(_Float16)b[1]; h[6]=(_Float16)b[2]; h[7]=(_Float16)b[3];
  return h;
}

__device__ __forceinline__ half8 load8_f32(const float* p) {
  f32x4 a = *(const f32x4*)p;
  f32x4 b = *(const f32x4*)(p + 4);
  return cvt8(a, b);
}

// ---------------------------------------------------------------------------
// k1: QKV = x @ W^T  (unchanged from baseline — proven)
// Q,K -> QK16 [8192 x 512] fp16 (Q cols 0-255, K cols 256-511)
// V   -> VT   [256 x 8192] fp16 (transposed, for PV B-frags)
// ---------------------------------------------------------------------------
__global__ __launch_bounds__(256) void qkv_kernel(
    const float* __restrict__ x, const float* __restrict__ Wq,
    const float* __restrict__ Wk, const float* __restrict__ Wv,
    _Float16* __restrict__ QK16, _Float16* __restrict__ VT)
{
  const int tid  = threadIdx.x;
  const int lane = tid & 63;
  const int wave = tid >> 6;
  const int c    = lane & 15;
  const int quad = lane >> 4;
  const int M0   = blockIdx.x * 128 + (wave >> 1) * 64;
  const int Nblk = blockIdx.y * 128 + (wave & 1) * 64;   // 0..767
  const int widx = Nblk >> 8;                            // 0=Q,1=K,2=V
  const int nloc = Nblk & 255;
  const float* W = (widx == 0) ? Wq : (widx == 1 ? Wk : Wv);

  f32x4 acc[4][4] = {};
  for (int k0 = 0; k0 < D_MODEL; k0 += 32) {
    half8 af[4], bf[4];
#pragma unroll
    for (int mt = 0; mt < 4; ++mt)
      af[mt] = load8_f32(&x[(size_t)(M0 + mt*16 + c) * D_MODEL + k0 + quad*8]);
#pragma unroll
    for (int nt = 0; nt < 4; ++nt)
      bf[nt] = load8_f32(&W[(size_t)(nloc + nt*16 + c) * D_MODEL + k0 + quad*8]);
#pragma unroll
    for (int mt = 0; mt < 4; ++mt)
#pragma unroll
      for (int nt = 0; nt < 4; ++nt)
        acc[mt][nt] = __builtin_amdgcn_mfma_f32_16x16x32_f16(af[mt], bf[nt], acc[mt][nt], 0, 0, 0);
  }

  if (widx < 2) {
#pragma unroll
    for (int mt = 0; mt < 4; ++mt)
#pragma unroll
      for (int nt = 0; nt < 4; ++nt) {
        const int col  = widx * 256 + nloc + nt*16 + c;
        const int row0 = M0 + mt*16 + quad*4;
#pragma unroll
        for (int r = 0; r < 4; ++r)
          QK16[(size_t)(row0 + r) * 512 + col] = (_Float16)acc[mt][nt][r];
      }
  } else {
#pragma unroll
    for (int mt = 0; mt < 4; ++mt)
#pragma unroll
      for (int nt = 0; nt < 4; ++nt) {
        const int d  = nloc + nt*16 + c;
        const int m0 = M0 + mt*16 + quad*4;
        half4 h;
        h[0]=(_Float16)acc[mt][nt][0]; h[1]=(_Float16)acc[mt][nt][1];
        h[2]=(_Float16)acc[mt][nt][2]; h[3]=(_Float16)acc[mt][nt][3];
        *(half4*)&VT[(size_t)d * NSEQ + m0] = h;
      }
  }
}

// ---------------------------------------------------------------------------
// k2: p = exp(Q@K^T / 16), row sums atomically accumulated into lsum.
// P16=true:  write unnormalized p as fp16 into workspace (128MB, half the
//            write traffic of f32) — pv reads it as direct MFMA A-frags.
// P16=false: legacy path, write f32 p into attn (pv normalizes in place).
// ---------------------------------------------------------------------------
template<bool P16>
__global__ __launch_bounds__(256) void score_kernel(
    const _Float16* __restrict__ QK16, void* __restrict__ Pout,
    float* __restrict__ lsum)
{
  const int tid  = threadIdx.x;
  const int lane = tid & 63;
  const int wave = tid >> 6;
  const int c    = lane & 15;
  const int quad = lane >> 4;
  const int M0   = blockIdx.x * 128 + (wave >> 1) * 64;
  const int N0   = blockIdx.y * 128 + (wave & 1) * 64;

  f32x4 acc[4][4] = {};
  for (int k0 = 0; k0 < 256; k0 += 32) {
    half8 af[4], bf[4];
#pragma unroll
    for (int mt = 0; mt < 4; ++mt)
      af[mt] = *(const half8*)&QK16[(size_t)(M0 + mt*16 + c) * 512 + k0 + quad*8];
#pragma unroll
    for (int nt = 0; nt < 4; ++nt)
      bf[nt] = *(const half8*)&QK16[(size_t)(N0 + nt*16 + c) * 512 + 256 + k0 + quad*8];
#pragma unroll
    for (int mt = 0; mt < 4; ++mt)
#pragma unroll
      for (int nt = 0; nt < 4; ++nt)
        acc[mt][nt] = __builtin_amdgcn_mfma_f32_16x16x32_f16(af[mt], bf[nt], acc[mt][nt], 0, 0, 0);
  }

  float psum[4][4] = {};   // [mt][r] partial row sums (this lane's 4 nt cols)
#pragma unroll
  for (int mt = 0; mt < 4; ++mt)
#pragma unroll
    for (int nt = 0; nt < 4; ++nt)
#pragma unroll
      for (int r = 0; r < 4; ++r) {
        const float p = __expf(acc[mt][nt][r] * 0.0625f);
        psum[mt][r] += p;
        const size_t idx = (size_t)(M0 + mt*16 + quad*4 + r) * NSEQ + N0 + nt*16 + c;
        if constexpr (P16) ((_Float16*)Pout)[idx] = (_Float16)p;
        else               ((float*)Pout)[idx]    = p;
      }

#pragma unroll
  for (int mt = 0; mt < 4; ++mt)
#pragma unroll
    for (int r = 0; r < 4; ++r) {
      float v = psum[mt][r];
      v += __shfl_xor(v, 1);
      v += __shfl_xor(v, 2);
      v += __shfl_xor(v, 4);
      v += __shfl_xor(v, 8);
      if (c == 0) atomicAdd(&lsum[M0 + mt*16 + quad*4 + r], v);
    }
}

// ---------------------------------------------------------------------------
// k3: attn = p * (1/lsum[row]) written once as f32 (final output);
//     cntx = (p @ V) * (1/lsum[row]) accumulated in registers, one pass.
// Restructured vs baseline:
//   * 32-row blocks x PV_GROUPS j-groups -> grid (256, 8) = 2048 blocks
//     (vs 512): ~16+ waves/CU resident instead of 8.
//   * NO LDS staging, NO per-iter barriers in the P16 path: row-major p16
//     at (row, j0+quad*8) IS the 16x16x32 A-fragment (contiguous half8).
//   * PV accumulates UNNORMALIZED p@V; 1/lsum applied in the epilogue, so
//     the attn write and the frag reads are fully independent.
//   * P16=false fallback (small ws): same structure, in-place f32
//     normalize, one barrier/iter between tile reads and tile writes.
// ---------------------------------------------------------------------------
template<bool P16>
__global__ __launch_bounds__(256) void pv_kernel(
    const void* __restrict__ Pin, float* __restrict__ attn,
    const float* __restrict__ lsum, const _Float16* __restrict__ VT,
    float* __restrict__ cntx)
{
  __shared__ float linv[32];
  const int tid  = threadIdx.x;
  const int lane = tid & 63;
  const int wave = tid >> 6;
  const int c    = lane & 15;
  const int quad = lane >> 4;
  const int M0   = blockIdx.x * 32;
  const int jb   = blockIdx.y * (NSEQ / PV_GROUPS);
  const int je   = jb + NSEQ / PV_GROUPS;
  const int D0   = wave * 64;            // this wave's 64 output d-cols
  const int nr   = tid >> 3;             // normalize row 0..31
  const int ncol = (tid & 7) * 8;        // normalize col offset 0..56

  if (tid < 32) linv[tid] = 1.0f / lsum[M0 + tid];
  __syncthreads();
  const float nscale = linv[nr];

  f32x4 acc[2][4] = {};
  for (int j0 = jb; j0 < je; j0 += 64) {
    // ---- read the 32x64 p tile: per-thread 8 elems for the attn write ----
    half8 np16; f32x4 np0, np1;
    if constexpr (P16) {
      np16 = *(const half8*)((const _Float16*)Pin + (size_t)(M0 + nr) * NSEQ + j0 + ncol);
    } else {
      const float* pr = (const float*)Pin + (size_t)(M0 + nr) * NSEQ + j0 + ncol;
      np0 = *(const f32x4*)pr; np1 = *(const f32x4*)(pr + 4);
    }

    // ---- per-wave MFMA fragments, direct from row-major p (no LDS) ----
    half8 af[2][2], bf[4][2];
#pragma unroll
    for (int h = 0; h < 2; ++h) {
#pragma unroll
      for (int mt = 0; mt < 2; ++mt) {
        if constexpr (P16) {
          af[mt][h] = *(const half8*)((const _Float16*)Pin +
                        (size_t)(M0 + mt*16 + c) * NSEQ + j0 + h*32 + quad*8);
        } else {
          const float* pa = (const float*)Pin +
                        (size_t)(M0 + mt*16 + c) * NSEQ + j0 + h*32 + quad*8;
          af[mt][h] = cvt8(*(const f32x4*)pa, *(const f32x4*)(pa + 4));
        }
      }
#pragma unroll
      for (int nt = 0; nt < 4; ++nt)
        bf[nt][h] = *(const half8*)&VT[(size_t)(D0 + nt*16 + c) * NSEQ + j0 + h*32 + quad*8];
    }

    if constexpr (!P16) __syncthreads();   // in-place: all reads before writes

    // ---- write normalized attn (final output), once ----
    {
      float* ar = attn + (size_t)(M0 + nr) * NSEQ + j0 + ncol;
      f32x4 w0, w1;
      if constexpr (P16) {
#pragma unroll
        for (int r = 0; r < 4; ++r) {
          w0[r] = (float)np16[r]     * nscale;
          w1[r] = (float)np16[r + 4] * nscale;
        }
      } else {
        w0 = np0 * nscale; w1 = np1 * nscale;
      }
      *(f32x4*)ar       = w0;
      *(f32x4*)(ar + 4) = w1;
    }

    // ---- PV MFMA (unnormalized accumulate) ----
#pragma unroll
    for (int h = 0; h < 2; ++h)
#pragma unroll
      for (int mt = 0; mt < 2; ++mt)
#pragma unroll
        for (int nt = 0; nt < 4; ++nt)
          acc[mt][nt] = __builtin_amdgcn_mfma_f32_16x16x32_f16(af[mt][h], bf[nt][h], acc[mt][nt], 0, 0, 0);
  }

  // epilogue: scale by 1/lsum, accumulate into cntx
#pragma unroll
  for (int mt = 0; mt < 2; ++mt)
#pragma unroll
    for (int r = 0; r < 4; ++r) {
      const float s = linv[mt*16 + quad*4 + r];
#pragma unroll
      for (int nt = 0; nt < 4; ++nt)
        atomicAdd(&cntx[(size_t)(M0 + mt*16 + quad*4 + r) * D_MODEL + D0 + nt*16 + c],
                  acc[mt][nt][r] * s);
    }
}

// ---------------------------------------------------------------------------
extern "C" void kernel_launch(void* const* d_in, const int* in_sizes, int n_in,
                              void* d_out, int out_size, void* d_ws, size_t ws_size,
                              hipStream_t stream)
{
  const float* x  = (const float*)d_in[0];
  const float* Wq = (const float*)d_in[1];
  const float* Wk = (const float*)d_in[2];
  const float* Wv = (const float*)d_in[3];

  float* cntx = (float*)d_out;                         // [8192 x 256]
  float* attn = cntx + (size_t)NSEQ * D_MODEL;         // [8192 x 8192]

  // ws layout: QK16 (8MB) | VT (4MB) | lsum (32KB) | P16 (128MB, if room)
  _Float16* QK16 = (_Float16*)d_ws;
  _Float16* VT   = QK16 + (size_t)NSEQ * 512;
  float*    lsum = (float*)(VT + (size_t)D_MODEL * NSEQ);
  _Float16* P16  = (_Float16*)(lsum + NSEQ);

  const size_t base_bytes = (size_t)NSEQ*512*2 + (size_t)D_MODEL*NSEQ*2 + (size_t)NSEQ*4;
  const bool big_ws = ws_size >= base_bytes + (size_t)NSEQ * NSEQ * 2;

  hipMemsetAsync(cntx, 0, sizeof(float) * (size_t)NSEQ * D_MODEL, stream);
  hipMemsetAsync(lsum, 0, sizeof(float) * NSEQ, stream);

  qkv_kernel<<<dim3(64, 6), 256, 0, stream>>>(x, Wq, Wk, Wv, QK16, VT);

  if (big_ws) {
    score_kernel<true><<<dim3(64, 64), 256, 0, stream>>>(QK16, (void*)P16, lsum);
    pv_kernel<true><<<dim3(NSEQ/32, PV_GROUPS), 256, 0, stream>>>(
        (const void*)P16, attn, lsum, VT, cntx);
  } else {
    score_kernel<false><<<dim3(64, 64), 256, 0, stream>>>(QK16, (void*)attn, lsum);
    pv_kernel<false><<<dim3(NSEQ/32, PV_GROUPS), 256, 0, stream>>>(
        (const void*)attn, attn, lsum, VT, cntx);
  }
}

// Round 2
// 642.237 us; speedup vs baseline: 1.0220x; 1.0220x over previous
//
#include <hip/hip_runtime.h>

#define D_MODEL 256
#define NSEQ    8192
#define PV_GROUPS 8

typedef _Float16 half8 __attribute__((ext_vector_type(8)));
typedef _Float16 half4 __attribute__((ext_vector_type(4)));
typedef float    f32x4 __attribute__((ext_vector_type(4)));

__device__ __forceinline__ half8 cvt8(f32x4 a, f32x4 b) {
  half8 h;
  h[0]=(_Float16)a[0]; h[1]=(_Float16)a[1]; h[2]=(_Float16)a[2]; h[3]=(_Float16)a[3];
  h[4]=(_Float16)b[0]; h[5]=(_Float16)b[1]; h[6]=(_Float16)b[2]; h[7]=(_Float16)b[3];
  return h;
}

__device__ __forceinline__ half8 load8_f32(const float* p) {
  f32x4 a = *(const f32x4*)p;
  f32x4 b = *(const f32x4*)(p + 4);
  return cvt8(a, b);
}

// ---------------------------------------------------------------------------
// k1: QKV = x @ W^T. Same per-wave 64x64 tile as before, but 1-wave blocks,
// grid (128,12) = 1536 resident waves (was 384 blocks = 1.5/CU) — latency
// hidden by TLP. x/W read from L3; compute is tiny.
// ---------------------------------------------------------------------------
__global__ __launch_bounds__(64, 3) void qkv_kernel(
    const float* __restrict__ x, const float* __restrict__ Wq,
    const float* __restrict__ Wk, const float* __restrict__ Wv,
    _Float16* __restrict__ QK16, _Float16* __restrict__ VT)
{
  const int lane = threadIdx.x & 63;
  const int c    = lane & 15;
  const int quad = lane >> 4;
  const int M0   = blockIdx.x * 64;
  const int Nblk = blockIdx.y * 64;                      // 0..704
  const int widx = Nblk >> 8;                            // 0=Q,1=K,2=V
  const int nloc = Nblk & 255;
  const float* W = (widx == 0) ? Wq : (widx == 1 ? Wk : Wv);

  f32x4 acc[4][4] = {};
  for (int k0 = 0; k0 < D_MODEL; k0 += 32) {
    half8 af[4], bf[4];
#pragma unroll
    for (int mt = 0; mt < 4; ++mt)
      af[mt] = load8_f32(&x[(size_t)(M0 + mt*16 + c) * D_MODEL + k0 + quad*8]);
#pragma unroll
    for (int nt = 0; nt < 4; ++nt)
      bf[nt] = load8_f32(&W[(size_t)(nloc + nt*16 + c) * D_MODEL + k0 + quad*8]);
#pragma unroll
    for (int mt = 0; mt < 4; ++mt)
#pragma unroll
      for (int nt = 0; nt < 4; ++nt)
        acc[mt][nt] = __builtin_amdgcn_mfma_f32_16x16x32_f16(af[mt], bf[nt], acc[mt][nt], 0, 0, 0);
  }

  if (widx < 2) {
#pragma unroll
    for (int mt = 0; mt < 4; ++mt)
#pragma unroll
      for (int nt = 0; nt < 4; ++nt) {
        const int col  = widx * 256 + nloc + nt*16 + c;
        const int row0 = M0 + mt*16 + quad*4;
#pragma unroll
        for (int r = 0; r < 4; ++r)
          QK16[(size_t)(row0 + r) * 512 + col] = (_Float16)acc[mt][nt][r];
      }
  } else {
#pragma unroll
    for (int mt = 0; mt < 4; ++mt)
#pragma unroll
      for (int nt = 0; nt < 4; ++nt) {
        const int d  = nloc + nt*16 + c;
        const int m0 = M0 + mt*16 + quad*4;
        half4 h;
        h[0]=(_Float16)acc[mt][nt][0]; h[1]=(_Float16)acc[mt][nt][1];
        h[2]=(_Float16)acc[mt][nt][2]; h[3]=(_Float16)acc[mt][nt][3];
        *(half4*)&VT[(size_t)d * NSEQ + m0] = h;
      }
  }
}

// ---------------------------------------------------------------------------
// k2: p = exp(Q@K^T / 16), row sums into lsum. K-loop now register
// double-buffered (2-deep): tile k+1's frags are in flight during MFMA on
// tile k, so the ~300cy L2/L3 latency on QK16 is covered per-wave.
// ---------------------------------------------------------------------------
template<bool P16>
__global__ __launch_bounds__(256, 3) void score_kernel(
    const _Float16* __restrict__ QK16, void* __restrict__ Pout,
    float* __restrict__ lsum)
{
  const int tid  = threadIdx.x;
  const int lane = tid & 63;
  const int wave = tid >> 6;
  const int c    = lane & 15;
  const int quad = lane >> 4;
  const int M0   = blockIdx.x * 128 + (wave >> 1) * 64;
  const int N0   = blockIdx.y * 128 + (wave & 1) * 64;

  f32x4 acc[4][4] = {};
  half8 afA[4], bfA[4], afB[4], bfB[4];

  auto ld = [&](half8 (&af)[4], half8 (&bf)[4], int k0) {
#pragma unroll
    for (int mt = 0; mt < 4; ++mt)
      af[mt] = *(const half8*)&QK16[(size_t)(M0 + mt*16 + c) * 512 + k0 + quad*8];
#pragma unroll
    for (int nt = 0; nt < 4; ++nt)
      bf[nt] = *(const half8*)&QK16[(size_t)(N0 + nt*16 + c) * 512 + 256 + k0 + quad*8];
  };
  auto mm = [&](half8 (&af)[4], half8 (&bf)[4]) {
#pragma unroll
    for (int mt = 0; mt < 4; ++mt)
#pragma unroll
      for (int nt = 0; nt < 4; ++nt)
        acc[mt][nt] = __builtin_amdgcn_mfma_f32_16x16x32_f16(af[mt], bf[nt], acc[mt][nt], 0, 0, 0);
  };

  ld(afA, bfA, 0);
#pragma unroll
  for (int k0 = 0; k0 < 256; k0 += 64) {
    ld(afB, bfB, k0 + 32);
    mm(afA, bfA);
    if (k0 + 64 < 256) ld(afA, bfA, k0 + 64);
    mm(afB, bfB);
  }

  float psum[4][4] = {};   // [mt][r] partial row sums (this lane's 4 nt cols)
#pragma unroll
  for (int mt = 0; mt < 4; ++mt)
#pragma unroll
    for (int nt = 0; nt < 4; ++nt)
#pragma unroll
      for (int r = 0; r < 4; ++r) {
        const float p = __expf(acc[mt][nt][r] * 0.0625f);
        psum[mt][r] += p;
        const size_t idx = (size_t)(M0 + mt*16 + quad*4 + r) * NSEQ + N0 + nt*16 + c;
        if constexpr (P16) ((_Float16*)Pout)[idx] = (_Float16)p;
        else               ((float*)Pout)[idx]    = p;
      }

#pragma unroll
  for (int mt = 0; mt < 4; ++mt)
#pragma unroll
    for (int r = 0; r < 4; ++r) {
      float v = psum[mt][r];
      v += __shfl_xor(v, 1);
      v += __shfl_xor(v, 2);
      v += __shfl_xor(v, 4);
      v += __shfl_xor(v, 8);
      if (c == 0) atomicAdd(&lsum[M0 + mt*16 + quad*4 + r], v);
    }
}

// ---------------------------------------------------------------------------
// k3 (P16 path): attn = p/lsum written once; cntx += (p@V)/lsum.
// Register double-buffered j-pipeline: while consuming tile A (attn write +
// 16 MFMA), tile B's 13 loads (p16 A-frags + VT B-frags + normalize row)
// are in flight — covers the ~900cy HBM latency of the p16 stream that
// round 1 exposed (VALUBusy 4%, VGPR 56 = compiler serialized the loop).
// ---------------------------------------------------------------------------
__global__ __launch_bounds__(256, 3) void pv_kernel_p16(
    const _Float16* __restrict__ P16, float* __restrict__ attn,
    const float* __restrict__ lsum, const _Float16* __restrict__ VT,
    float* __restrict__ cntx)
{
  __shared__ float linv[32];
  const int tid  = threadIdx.x;
  const int lane = tid & 63;
  const int wave = tid >> 6;
  const int c    = lane & 15;
  const int quad = lane >> 4;
  const int M0   = blockIdx.x * 32;
  const int jb   = blockIdx.y * (NSEQ / PV_GROUPS);
  const int je   = jb + NSEQ / PV_GROUPS;
  const int D0   = wave * 64;
  const int nr   = tid >> 3;            // normalize row 0..31
  const int ncol = (tid & 7) * 8;       // normalize col offset 0..56

  if (tid < 32) linv[tid] = 1.0f / lsum[M0 + tid];
  __syncthreads();
  const float nscale = linv[nr];

  f32x4 acc[2][4] = {};
  half8 afA[2][2], bfA[4][2], npA;
  half8 afB[2][2], bfB[4][2], npB;

  auto ld = [&](half8 (&af)[2][2], half8 (&bf)[4][2], half8& np, int j0) {
    np = *(const half8*)&P16[(size_t)(M0 + nr) * NSEQ + j0 + ncol];
#pragma unroll
    for (int h = 0; h < 2; ++h) {
#pragma unroll
      for (int mt = 0; mt < 2; ++mt)
        af[mt][h] = *(const half8*)&P16[(size_t)(M0 + mt*16 + c) * NSEQ + j0 + h*32 + quad*8];
#pragma unroll
      for (int nt = 0; nt < 4; ++nt)
        bf[nt][h] = *(const half8*)&VT[(size_t)(D0 + nt*16 + c) * NSEQ + j0 + h*32 + quad*8];
    }
  };
  auto consume = [&](half8 (&af)[2][2], half8 (&bf)[4][2], half8& np, int j0) {
    f32x4 w0, w1;
#pragma unroll
    for (int r = 0; r < 4; ++r) {
      w0[r] = (float)np[r]     * nscale;
      w1[r] = (float)np[r + 4] * nscale;
    }
    float* ar = attn + (size_t)(M0 + nr) * NSEQ + j0 + ncol;
    *(f32x4*)ar       = w0;
    *(f32x4*)(ar + 4) = w1;
#pragma unroll
    for (int h = 0; h < 2; ++h)
#pragma unroll
      for (int mt = 0; mt < 2; ++mt)
#pragma unroll
        for (int nt = 0; nt < 4; ++nt)
          acc[mt][nt] = __builtin_amdgcn_mfma_f32_16x16x32_f16(af[mt][h], bf[nt][h], acc[mt][nt], 0, 0, 0);
  };

  ld(afA, bfA, npA, jb);
  for (int j0 = jb; j0 < je; j0 += 128) {
    ld(afB, bfB, npB, j0 + 64);
    consume(afA, bfA, npA, j0);
    if (j0 + 128 < je) ld(afA, bfA, npA, j0 + 128);
    consume(afB, bfB, npB, j0 + 64);
  }

  // epilogue: scale by 1/lsum, accumulate into cntx
#pragma unroll
  for (int mt = 0; mt < 2; ++mt)
#pragma unroll
    for (int r = 0; r < 4; ++r) {
      const float s = linv[mt*16 + quad*4 + r];
#pragma unroll
      for (int nt = 0; nt < 4; ++nt)
        atomicAdd(&cntx[(size_t)(M0 + mt*16 + quad*4 + r) * D_MODEL + D0 + nt*16 + c],
                  acc[mt][nt][r] * s);
    }
}

// ---------------------------------------------------------------------------
// k3 fallback (small ws): in-place f32 normalize + PV, unchanged semantics.
// ---------------------------------------------------------------------------
__global__ __launch_bounds__(256) void pv_kernel_f32(
    const float* __restrict__ Pin, float* __restrict__ attn,
    const float* __restrict__ lsum, const _Float16* __restrict__ VT,
    float* __restrict__ cntx)
{
  __shared__ float linv[32];
  const int tid  = threadIdx.x;
  const int lane = tid & 63;
  const int wave = tid >> 6;
  const int c    = lane & 15;
  const int quad = lane >> 4;
  const int M0   = blockIdx.x * 32;
  const int jb   = blockIdx.y * (NSEQ / PV_GROUPS);
  const int je   = jb + NSEQ / PV_GROUPS;
  const int D0   = wave * 64;
  const int nr   = tid >> 3;
  const int ncol = (tid & 7) * 8;

  if (tid < 32) linv[tid] = 1.0f / lsum[M0 + tid];
  __syncthreads();
  const float nscale = linv[nr];

  f32x4 acc[2][4] = {};
  for (int j0 = jb; j0 < je; j0 += 64) {
    const float* pr = Pin + (size_t)(M0 + nr) * NSEQ + j0 + ncol;
    f32x4 np0 = *(const f32x4*)pr;
    f32x4 np1 = *(const f32x4*)(pr + 4);

    half8 af[2][2], bf[4][2];
#pragma unroll
    for (int h = 0; h < 2; ++h) {
#pragma unroll
      for (int mt = 0; mt < 2; ++mt) {
        const float* pa = Pin + (size_t)(M0 + mt*16 + c) * NSEQ + j0 + h*32 + quad*8;
        af[mt][h] = cvt8(*(const f32x4*)pa, *(const f32x4*)(pa + 4));
      }
#pragma unroll
      for (int nt = 0; nt < 4; ++nt)
        bf[nt][h] = *(const half8*)&VT[(size_t)(D0 + nt*16 + c) * NSEQ + j0 + h*32 + quad*8];
    }

    __syncthreads();   // all reads of this tile before in-place writes

    float* ar = attn + (size_t)(M0 + nr) * NSEQ + j0 + ncol;
    *(f32x4*)ar       = np0 * nscale;
    *(f32x4*)(ar + 4) = np1 * nscale;

#pragma unroll
    for (int h = 0; h < 2; ++h)
#pragma unroll
      for (int mt = 0; mt < 2; ++mt)
#pragma unroll
        for (int nt = 0; nt < 4; ++nt)
          acc[mt][nt] = __builtin_amdgcn_mfma_f32_16x16x32_f16(af[mt][h], bf[nt][h], acc[mt][nt], 0, 0, 0);
  }

#pragma unroll
  for (int mt = 0; mt < 2; ++mt)
#pragma unroll
    for (int r = 0; r < 4; ++r) {
      const float s = linv[mt*16 + quad*4 + r];
#pragma unroll
      for (int nt = 0; nt < 4; ++nt)
        atomicAdd(&cntx[(size_t)(M0 + mt*16 + quad*4 + r) * D_MODEL + D0 + nt*16 + c],
                  acc[mt][nt][r] * s);
    }
}

// ---------------------------------------------------------------------------
extern "C" void kernel_launch(void* const* d_in, const int* in_sizes, int n_in,
                              void* d_out, int out_size, void* d_ws, size_t ws_size,
                              hipStream_t stream)
{
  const float* x  = (const float*)d_in[0];
  const float* Wq = (const float*)d_in[1];
  const float* Wk = (const float*)d_in[2];
  const float* Wv = (const float*)d_in[3];

  float* cntx = (float*)d_out;                         // [8192 x 256]
  float* attn = cntx + (size_t)NSEQ * D_MODEL;         // [8192 x 8192]

  // ws layout: QK16 (8MB) | VT (4MB) | lsum (32KB) | P16 (128MB, if room)
  _Float16* QK16 = (_Float16*)d_ws;
  _Float16* VT   = QK16 + (size_t)NSEQ * 512;
  float*    lsum = (float*)(VT + (size_t)D_MODEL * NSEQ);
  _Float16* P16  = (_Float16*)(lsum + NSEQ);

  const size_t base_bytes = (size_t)NSEQ*512*2 + (size_t)D_MODEL*NSEQ*2 + (size_t)NSEQ*4;
  const bool big_ws = ws_size >= base_bytes + (size_t)NSEQ * NSEQ * 2;

  hipMemsetAsync(cntx, 0, sizeof(float) * (size_t)NSEQ * D_MODEL, stream);
  hipMemsetAsync(lsum, 0, sizeof(float) * NSEQ, stream);

  qkv_kernel<<<dim3(128, 12), 64, 0, stream>>>(x, Wq, Wk, Wv, QK16, VT);

  if (big_ws) {
    score_kernel<true><<<dim3(64, 64), 256, 0, stream>>>(QK16, (void*)P16, lsum);
    pv_kernel_p16<<<dim3(NSEQ/32, PV_GROUPS), 256, 0, stream>>>(P16, attn, lsum, VT, cntx);
  } else {
    score_kernel<false><<<dim3(64, 64), 256, 0, stream>>>(QK16, (void*)attn, lsum);
    pv_kernel_f32<<<dim3(NSEQ/32, PV_GROUPS), 256, 0, stream>>>(attn, attn, lsum, VT, cntx);
  }
}